// Round 1
// baseline (321.783 us; speedup 1.0000x reference)
//
#include <hip/hip_runtime.h>
#include <stdint.h>

#define H_ 192
#define W_ 192
#define C_ 64
#define EPS_F 1e-8f
#define TILE 16
#define CHUNK 256
#define NSLICE 16
#define NBUCKET 256
#define MAXCHUNK 64

typedef unsigned long long ull;

// Output layout (floats), concatenated in reference return order:
// feats (H*W*C) | p2f (H*W) | zbuf (H*W) | bary (H*W*3) | dists (H*W)
#define OFF_FEATS 0
#define OFF_P2F   (H_*W_*C_)
#define OFF_ZBUF  (OFF_P2F + H_*W_)
#define OFF_BARY  (OFF_ZBUF + H_*W_)
#define OFF_DIST  (OFF_BARY + H_*W_*3)

// IEEE-exact ops (block FMA contraction; match numpy float32 op-for-op)
__device__ __forceinline__ float xm(float a, float b){ return __fmul_rn(a,b); }
__device__ __forceinline__ float xa(float a, float b){ return __fadd_rn(a,b); }
__device__ __forceinline__ float xsb(float a, float b){ return __fsub_rn(a,b); }
__device__ __forceinline__ float xd(float a, float b){ return __fdiv_rn(a,b); }

__device__ __forceinline__ float pixcoord(int i, float dim){
    float t = xa(xm(2.0f, (float)i), 1.0f);
    return xsb(1.0f, xd(t, dim));
}

// monotone float<->uint encode for signed-float atomic min/max
__device__ __forceinline__ unsigned fenc(float f){
    unsigned b = __float_as_uint(f);
    return (b & 0x80000000u) ? ~b : (b | 0x80000000u);
}
__device__ __forceinline__ float fdec(unsigned e){
    unsigned b = (e & 0x80000000u) ? (e & 0x7FFFFFFFu) : ~e;
    return __uint_as_float(b);
}

// depth bucket: fixed mapping (perf-only; correctness holds for any mapping)
__device__ __forceinline__ int zbucket(float zmn){
    int b = (int)((zmn - 2.0f) * 64.0f);
    return b < 0 ? 0 : (b > 254 ? 254 : b);
}

// Fused: key/hist/chunkmin/gbbox init + vertex transform
__global__ void k_init(const float* __restrict__ pos, const float* __restrict__ K,
                       const float* __restrict__ RT, float* __restrict__ verts,
                       ull* __restrict__ keys, unsigned* __restrict__ hist,
                       unsigned* __restrict__ chunkmin, unsigned* __restrict__ gbb, int V){
    int i = blockIdx.x*blockDim.x + threadIdx.x;
    if (i < H_*W_) keys[i] = 0xFFFFFFFFFFFFFFFFULL;
    if (i < NBUCKET) hist[i] = 0u;
    if (i < MAXCHUNK) chunkmin[i] = 0x7F800000u;   // +INF bits
    if (i == 0){ gbb[0]=0xFFFFFFFFu; gbb[1]=0u; gbb[2]=0xFFFFFFFFu; gbb[3]=0u; }
    if (i >= V) return;
    float p0 = pos[3*i+0], p1 = pos[3*i+1], p2 = pos[3*i+2];
    const float sgn[3] = {-1.f, -1.f, 1.f};
    float vv[3];
    #pragma unroll
    for (int j=0;j<3;j++){
        float rp0 = xm(RT[j*4+0], sgn[j]);
        float rp1 = xm(RT[j*4+1], sgn[j]);
        float rp2 = xm(RT[j*4+2], sgn[j]);
        float s = xa(xa(xm(p0,rp0), xm(p1,rp1)), xm(p2,rp2));
        vv[j] = xa(s, xm(RT[j*4+3], sgn[j]));
    }
    float z = vv[2];
    const float scale = 96.0f;
    float fx = xd(K[0], scale);
    float fy = xd(K[4], scale);
    float p0x = -xd(xsb(K[2], 96.0f), scale);
    float p0y = -xd(xsb(K[5], 96.0f), scale);
    float xn = xa(xd(xm(fx, vv[0]), z), p0x);
    float yn = xa(xd(xm(fy, vv[1]), z), p0y);
    verts[4*i+0] = xn; verts[4*i+1] = yn; verts[4*i+2] = z; verts[4*i+3] = 0.f;
}

// Pre-pass: depth-bucket histogram + global screen bbox of live faces
__global__ __launch_bounds__(256) void k_prehist(const int* __restrict__ faces,
        const float* __restrict__ verts, unsigned* __restrict__ hist,
        unsigned* __restrict__ gbb, int Fn){
    __shared__ unsigned lh[NBUCKET];
    int t = threadIdx.x;
    lh[t] = 0u;
    __syncthreads();
    int f = blockIdx.x*256 + t;
    float bxmn=INFINITY, bxmx=-INFINITY, bymn=INFINITY, bymx=-INFINITY;
    if (f < Fn){
        int i0 = faces[3*f+0], i1 = faces[3*f+1], i2 = faces[3*f+2];
        float x0=verts[4*i0+0], y0=verts[4*i0+1], z0=verts[4*i0+2];
        float x1=verts[4*i1+0], y1=verts[4*i1+1], z1=verts[4*i1+2];
        float x2=verts[4*i2+0], y2=verts[4*i2+1], z2=verts[4*i2+2];
        float area = xsb(xm(xsb(x1,x0), xsb(y2,y0)), xm(xsb(y1,y0), xsb(x2,x0)));
        bool ok = (area > EPS_F) && (z0 > 0.f) && (z1 > 0.f) && (z2 > 0.f);
        int b = 255;
        if (ok){
            float zmn = fminf(z0, fminf(z1, z2));
            b = zbucket(zmn);
            bxmn = fminf(x0, fminf(x1, x2)) - 1e-4f;
            bxmx = fmaxf(x0, fmaxf(x1, x2)) + 1e-4f;
            bymn = fminf(y0, fminf(y1, y2)) - 1e-4f;
            bymx = fmaxf(y0, fmaxf(y1, y2)) + 1e-4f;
        }
        atomicAdd(&lh[b], 1u);
    }
    // wave-reduce the bbox, one atomic set per wave
    #pragma unroll
    for (int s=1; s<64; s<<=1){
        bxmn = fminf(bxmn, __shfl_xor(bxmn, s, 64));
        bxmx = fmaxf(bxmx, __shfl_xor(bxmx, s, 64));
        bymn = fminf(bymn, __shfl_xor(bymn, s, 64));
        bymx = fmaxf(bymx, __shfl_xor(bymx, s, 64));
    }
    if ((t & 63) == 0){
        atomicMin(&gbb[0], fenc(bxmn));
        atomicMax(&gbb[1], fenc(bxmx));
        atomicMin(&gbb[2], fenc(bymn));
        atomicMax(&gbb[3], fenc(bymx));
    }
    __syncthreads();
    unsigned cc = lh[t];
    if (cc) atomicAdd(&hist[t], cc);
}

// Exclusive prefix over 256 bucket counts (single block)
__global__ __launch_bounds__(256) void k_scan(unsigned* __restrict__ hist){
    __shared__ unsigned s[NBUCKET];
    int t = threadIdx.x;
    unsigned v = hist[t];
    s[t] = v;
    __syncthreads();
    for (int d=1; d<NBUCKET; d<<=1){
        unsigned u = (t >= d) ? s[t-d] : 0u;
        __syncthreads();
        s[t] += u;
        __syncthreads();
    }
    hist[t] = s[t] - v;   // exclusive offsets; scatter's atomicAdd consumes them
}

// Face record (16 floats), written in depth-sorted order:
// q0: x0,y0,x1,y1 | q1: x2,y2,z0,z1 | q2: z2,ia,zmin,fidbits | q3: xmin,xmax,ymin,ymax
__global__ __launch_bounds__(256) void k_scatter(const int* __restrict__ faces,
        const float* __restrict__ verts, float* __restrict__ rec,
        unsigned* __restrict__ hist, unsigned* __restrict__ chunkmin, int Fn){
    int f = blockIdx.x*blockDim.x + threadIdx.x;
    if (f >= Fn) return;
    int i0 = faces[3*f+0], i1 = faces[3*f+1], i2 = faces[3*f+2];
    float x0=verts[4*i0+0], y0=verts[4*i0+1], z0=verts[4*i0+2];
    float x1=verts[4*i1+0], y1=verts[4*i1+1], z1=verts[4*i1+2];
    float x2=verts[4*i2+0], y2=verts[4*i2+1], z2=verts[4*i2+2];
    float area = xsb(xm(xsb(x1,x0), xsb(y2,y0)), xm(xsb(y1,y0), xsb(x2,x0)));
    bool ok = (area > EPS_F) && (z0 > 0.f) && (z1 > 0.f) && (z2 > 0.f);
    float inv_area = ok ? xd(1.0f, area) : 0.0f;
    float xmn, xmx, ymn, ymx, zmn;
    int b;
    if (ok){
        xmn = fminf(x0, fminf(x1, x2)) - 1e-4f;
        xmx = fmaxf(x0, fmaxf(x1, x2)) + 1e-4f;
        ymn = fminf(y0, fminf(y1, y2)) - 1e-4f;
        ymx = fmaxf(y0, fmaxf(y1, y2)) + 1e-4f;
        zmn = fminf(z0, fminf(z1, z2));
        b = zbucket(zmn);
    } else {
        xmn = INFINITY; xmx = -INFINITY; ymn = INFINITY; ymx = -INFINITY;
        zmn = INFINITY;
        b = 255;
    }
    unsigned pos = atomicAdd(&hist[b], 1u);
    float4* q = (float4*)(rec + (size_t)pos*16);
    q[0] = make_float4(x0, y0, x1, y1);
    q[1] = make_float4(x2, y2, z0, z1);
    q[2] = make_float4(z2, inv_area, zmn, __int_as_float(f));
    q[3] = make_float4(xmn, xmx, ymn, ymx);
    if ((pos >> 8) < MAXCHUNK)
        atomicMin(&chunkmin[pos >> 8], __float_as_uint(zmn));  // positive floats: uint order == float order
}

__global__ __launch_bounds__(256) void k_raster(const float* __restrict__ rec,
        const unsigned* __restrict__ chunkmin, const unsigned* __restrict__ gbb,
        ull* __restrict__ keys, int Fn){
    __shared__ float lds[CHUNK*12];   // 12 floats per face
    __shared__ float zl[CHUNK];       // zmin of survivors, compacted
    __shared__ int   slist[CHUNK];    // survivor chunk-local indices, compacted
    __shared__ int   wcnt[4];
    __shared__ float suff[MAXCHUNK];  // suffix-min of chunk zmins
    int tid = threadIdx.x;
    int nchunk = Fn / CHUNK;
    // wave0: inclusive suffix-min over chunk zmins (64 lanes, shfl scan)
    if (tid < MAXCHUNK){
        float v = (tid < nchunk) ? __uint_as_float(chunkmin[tid]) : INFINITY;
        #pragma unroll
        for (int s=1; s<MAXCHUNK; s<<=1){
            int src = tid + s; if (src > MAXCHUNK-1) src = MAXCHUNK-1;
            float o = __shfl(v, src, 64);
            v = fminf(v, o);
        }
        suff[tid] = v;
    }
    int ix = blockIdx.x*TILE + (tid & 15);
    int iy = blockIdx.y*TILE + (tid >> 4);
    int pix = iy*W_ + ix;
    float px = pixcoord(ix, (float)W_);
    float py = pixcoord(iy, (float)H_);
    float tx_hi = pixcoord(blockIdx.x*TILE,          (float)W_);
    float tx_lo = pixcoord(blockIdx.x*TILE + TILE-1, (float)W_);
    float ty_hi = pixcoord(blockIdx.y*TILE,          (float)H_);
    float ty_lo = pixcoord(blockIdx.y*TILE + TILE-1, (float)H_);
    float gx0 = fdec(gbb[0]), gx1 = fdec(gbb[1]);
    float gy0 = fdec(gbb[2]), gy1 = fdec(gbb[3]);
    // pixel outside the union of all live-face bboxes can never be hit
    bool alive = (px >= gx0) && (px <= gx1) && (py >= gy0) && (py <= gy1);
    int lane = tid & 63, wv = tid >> 6;

    float zcut = INFINITY;       // skip threshold: min(local best z, global best z)
    ull localkey = 0xFFFFFFFFFFFFFFFFULL;  // only locally-found candidates (written back)
    __syncthreads();             // suff[] ready

    for (int c = (int)blockIdx.z; c < nchunk; c += NSLICE){
        // share depth convergence across slice blocks (stale reads are conservative)
        ull g = __hip_atomic_load(&keys[pix], __ATOMIC_RELAXED, __HIP_MEMORY_SCOPE_AGENT);
        float zg = __uint_as_float((unsigned)(g >> 32));   // NaN if key empty -> fminf ignores
        zcut = fminf(zcut, zg);
        // block-wide break: every remaining face (zmin >= suff[c]) would be pre-check-skipped
        float sc = (c < MAXCHUNK) ? suff[c] : 0.0f;
        int done = (!alive || !(xm(sc, 0.999f) < zcut)) ? 1 : 0;
        if (__syncthreads_and(done)) break;    // barrier also protects lds reuse

        int base = c*CHUNK;
        const float4* gq = (const float4*)(rec + (size_t)(base + tid)*16);
        float4 q0 = gq[0], q1 = gq[1], q2 = gq[2], q3 = gq[3];
        // bbox-vs-tile overlap; dead faces have empty bbox -> rejected
        bool keep = (q3.x <= tx_hi) && (q3.y >= tx_lo) && (q3.z <= ty_hi) && (q3.w >= ty_lo);
        float4* l = (float4*)(lds + tid*12);
        l[0] = q0; l[1] = q1; l[2] = q2;
        ull m = __ballot(keep);
        if (lane == 0) wcnt[wv] = __popcll(m);
        __syncthreads();
        int basecnt = 0;
        #pragma unroll
        for (int w2 = 0; w2 < 4; ++w2) if (w2 < wv) basecnt += wcnt[w2];
        if (keep){
            int p = basecnt + __popcll(m & ((1ULL << lane) - 1ULL));
            slist[p] = tid;
            zl[p] = q2.z;   // zmin
        }
        int nsurv = wcnt[0] + wcnt[1] + wcnt[2] + wcnt[3];
        __syncthreads();

        for (int k = 0; k < nsurv; k++){
            float zminf = zl[k];
            // conservative depth pre-check (margin 0.999 covers interpolation rounding)
            if (!(xm(zminf, 0.999f) < zcut)) continue;
            int j = slist[k];
            const float* r = lds + j*12;
            float x0=r[0], y0=r[1], x1=r[2], y1=r[3], x2=r[4], y2=r[5];
            float dx0=xsb(x0,px), dx1=xsb(x1,px), dx2=xsb(x2,px);
            float dy0=xsb(y0,py), dy1=xsb(y1,py), dy2=xsb(y2,py);
            // edge functions: sign(e_i) == sign(w_i) since ia>0
            float e0 = xsb(xm(dx1,dy2), xm(dy1,dx2));
            float e1 = xsb(xm(dx2,dy0), xm(dy2,dx0));
            float e2 = xsb(xm(dx0,dy1), xm(dy0,dx1));
            if (e0 >= 0.f && e1 >= 0.f && e2 >= 0.f){
                float z0=r[6], z1=r[7], z2=r[8], ia=r[9];
                float w0 = xm(e0, ia), w1 = xm(e1, ia), w2 = xm(e2, ia);
                float l0 = xm(xm(w0,z1),z2);
                float l1 = xm(xm(z0,w1),z2);
                float l2 = xm(xm(z0,z1),w2);
                float s  = xa(xa(l0,l1),l2);
                float dn = (s == 0.f) ? 1.0f : s;
                float b0 = fmaxf(xd(l0,dn), 0.f);
                float b1 = fmaxf(xd(l1,dn), 0.f);
                float b2 = fmaxf(xd(l2,dn), 0.f);
                float bs = fmaxf(xa(xa(b0,b1),b2), EPS_F);
                b0 = xd(b0,bs); b1 = xd(b1,bs); b2 = xd(b2,bs);
                float zp = xa(xa(xm(b0,z0),xm(b1,z1)),xm(b2,z2));
                // packed (z, orig_fid) key: exact argmin-first tie semantics
                ull ck = (((ull)__float_as_uint(zp)) << 32) | (unsigned)__float_as_int(r[11]);
                if (ck < localkey) localkey = ck;
                zcut = fminf(zcut, zp);
            }
        }
    }
    if (localkey != 0xFFFFFFFFFFFFFFFFULL) atomicMin(&keys[pix], localkey);
}

// Fused resolve + shade: 64 lanes per pixel (lane = channel), 4 pixels/block.
// Face record rebuilt from verts/faces (rec is depth-sorted; keys hold orig fid).
__global__ __launch_bounds__(256) void k_post(const ull* __restrict__ keys,
        const float* __restrict__ verts, const float* __restrict__ feats,
        const int* __restrict__ faces, float* __restrict__ out){
    int grp = threadIdx.x >> 6;
    int c = threadIdx.x & 63;
    int pix = blockIdx.x*4 + grp;
    float* p2f  = out + OFF_P2F;
    float* zbuf = out + OFF_ZBUF;
    float* bary = out + OFF_BARY;
    float* dist = out + OFF_DIST;
    ull key = keys[pix];
    if (key == 0xFFFFFFFFFFFFFFFFULL){
        out[OFF_FEATS + pix*C_ + c] = 0.0f;
        if (c == 0){
            p2f[pix] = -1.0f; zbuf[pix] = -1.0f; dist[pix] = -1.0f;
        }
        if (c < 3) bary[3*pix+c] = -1.0f;
        return;
    }
    int f = (int)(key & 0xFFFFFFFFu);
    float z = __uint_as_float((unsigned)(key >> 32));
    int ix = pix % W_, iy = pix / W_;
    float px = pixcoord(ix, (float)W_);
    float py = pixcoord(iy, (float)H_);
    int i0 = faces[3*f+0], i1 = faces[3*f+1], i2 = faces[3*f+2];
    float x0=verts[4*i0+0], y0=verts[4*i0+1], z0=verts[4*i0+2];
    float x1=verts[4*i1+0], y1=verts[4*i1+1], z1=verts[4*i1+2];
    float x2=verts[4*i2+0], y2=verts[4*i2+1], z2=verts[4*i2+2];
    float area = xsb(xm(xsb(x1,x0), xsb(y2,y0)), xm(xsb(y1,y0), xsb(x2,x0)));
    float ia = xd(1.0f, area);   // face is a hit -> guaranteed ok, area > EPS
    float w0 = xm(xsb(xm(xsb(x1,px),xsb(y2,py)), xm(xsb(y1,py),xsb(x2,px))), ia);
    float w1 = xm(xsb(xm(xsb(x2,px),xsb(y0,py)), xm(xsb(y2,py),xsb(x0,px))), ia);
    float w2 = xm(xsb(xm(xsb(x0,px),xsb(y1,py)), xm(xsb(y0,py),xsb(x1,px))), ia);
    float l0 = xm(xm(w0,z1),z2);
    float l1 = xm(xm(z0,w1),z2);
    float l2 = xm(xm(z0,z1),w2);
    float s  = xa(xa(l0,l1),l2);
    float dn = (s == 0.f) ? 1.0f : s;
    float b0 = fmaxf(xd(l0,dn), 0.f);
    float b1 = fmaxf(xd(l1,dn), 0.f);
    float b2 = fmaxf(xd(l2,dn), 0.f);
    float bs = fmaxf(xa(xa(b0,b1),b2), EPS_F);
    b0 = xd(b0,bs); b1 = xd(b1,bs); b2 = xd(b2,bs);
    float res = xa(xa(xm(b0, feats[i0*C_ + c]), xm(b1, feats[i1*C_ + c])),
                   xm(b2, feats[i2*C_ + c]));
    out[OFF_FEATS + pix*C_ + c] = res;
    if (c == 0){
        p2f[pix] = (float)f; zbuf[pix] = z; dist[pix] = 0.0f;
    }
    if (c < 3){
        float bb = (c == 0) ? b0 : ((c == 1) ? b1 : b2);
        bary[3*pix+c] = bb;
    }
}

extern "C" void kernel_launch(void* const* d_in, const int* in_sizes, int n_in,
                              void* d_out, int out_size, void* d_ws, size_t ws_size,
                              hipStream_t stream) {
    const float* positions = (const float*)d_in[0];
    const float* features  = (const float*)d_in[1];
    const int*   faces     = (const int*)  d_in[2];
    const float* K         = (const float*)d_in[3];
    const float* RT        = (const float*)d_in[4];
    int V  = in_sizes[0] / 3;   // 8192
    int Fn = in_sizes[2] / 3;   // 16384

    float* verts = (float*)d_ws;                        // V*4 floats
    float* rec   = verts + (size_t)V*4;                 // Fn*16 floats (depth-sorted)
    ull*   keys  = (ull*)(rec + (size_t)Fn*16);         // H*W keys
    unsigned* hist     = (unsigned*)(keys + H_*W_);     // 256 bucket counts/offsets
    unsigned* chunkmin = hist + NBUCKET;                // 64 chunk zmins (uint bits)
    unsigned* gbb      = chunkmin + MAXCHUNK;           // global bbox (enc uint x4)

    int initN = H_*W_;  // covers keys (36864), verts (8192), hist/chunkmin/gbb
    k_init<<<(initN+255)/256, 256, 0, stream>>>(positions, K, RT, verts, keys, hist, chunkmin, gbb, V);
    k_prehist<<<(Fn+255)/256, 256, 0, stream>>>(faces, verts, hist, gbb, Fn);
    k_scan<<<1, 256, 0, stream>>>(hist);
    k_scatter<<<(Fn+255)/256, 256, 0, stream>>>(faces, verts, rec, hist, chunkmin, Fn);
    dim3 rg(W_/TILE, H_/TILE, NSLICE);
    k_raster<<<rg, dim3(256,1,1), 0, stream>>>(rec, chunkmin, gbb, keys, Fn);
    k_post<<<(H_*W_)/4, 256, 0, stream>>>(keys, verts, features, faces, (float*)d_out);
}

// Round 2
// 247.128 us; speedup vs baseline: 1.3021x; 1.3021x over previous
//
#include <hip/hip_runtime.h>
#include <stdint.h>

#define H_ 192
#define W_ 192
#define C_ 64
#define EPS_F 1e-8f
#define TILE 16
#define CHUNK 256
#define NSLICE 16
#define NBUCKET 256
#define MAXCHUNK 64

typedef unsigned long long ull;

// Output layout (floats), concatenated in reference return order:
// feats (H*W*C) | p2f (H*W) | zbuf (H*W) | bary (H*W*3) | dists (H*W)
#define OFF_FEATS 0
#define OFF_P2F   (H_*W_*C_)
#define OFF_ZBUF  (OFF_P2F + H_*W_)
#define OFF_BARY  (OFF_ZBUF + H_*W_)
#define OFF_DIST  (OFF_BARY + H_*W_*3)

// IEEE-exact ops (block FMA contraction; match numpy float32 op-for-op)
__device__ __forceinline__ float xm(float a, float b){ return __fmul_rn(a,b); }
__device__ __forceinline__ float xa(float a, float b){ return __fadd_rn(a,b); }
__device__ __forceinline__ float xsb(float a, float b){ return __fsub_rn(a,b); }
__device__ __forceinline__ float xd(float a, float b){ return __fdiv_rn(a,b); }

__device__ __forceinline__ float pixcoord(int i, float dim){
    float t = xa(xm(2.0f, (float)i), 1.0f);
    return xsb(1.0f, xd(t, dim));
}

// monotone float<->uint encode for signed-float atomic min/max
__device__ __forceinline__ unsigned fenc(float f){
    unsigned b = __float_as_uint(f);
    return (b & 0x80000000u) ? ~b : (b | 0x80000000u);
}
__device__ __forceinline__ float fdec(unsigned e){
    unsigned b = (e & 0x80000000u) ? (e & 0x7FFFFFFFu) : ~e;
    return __uint_as_float(b);
}

// depth bucket: fixed mapping (perf-only; correctness holds for any mapping)
__device__ __forceinline__ int zbucket(float zmn){
    int b = (int)((zmn - 2.0f) * 64.0f);
    return b < 0 ? 0 : (b > 254 ? 254 : b);
}

// Fused: key/hist/chunkmin/gbbox init + vertex transform
__global__ void k_init(const float* __restrict__ pos, const float* __restrict__ K,
                       const float* __restrict__ RT, float* __restrict__ verts,
                       ull* __restrict__ keys, unsigned* __restrict__ hist,
                       unsigned* __restrict__ chunkmin, unsigned* __restrict__ gbb, int V){
    int i = blockIdx.x*blockDim.x + threadIdx.x;
    if (i < H_*W_) keys[i] = 0xFFFFFFFFFFFFFFFFULL;
    if (i < NBUCKET) hist[i] = 0u;
    if (i < MAXCHUNK) chunkmin[i] = 0x7F800000u;   // +INF bits
    if (i == 0){ gbb[0]=0xFFFFFFFFu; gbb[1]=0u; gbb[2]=0xFFFFFFFFu; gbb[3]=0u; }
    if (i >= V) return;
    float p0 = pos[3*i+0], p1 = pos[3*i+1], p2 = pos[3*i+2];
    const float sgn[3] = {-1.f, -1.f, 1.f};
    float vv[3];
    #pragma unroll
    for (int j=0;j<3;j++){
        float rp0 = xm(RT[j*4+0], sgn[j]);
        float rp1 = xm(RT[j*4+1], sgn[j]);
        float rp2 = xm(RT[j*4+2], sgn[j]);
        float s = xa(xa(xm(p0,rp0), xm(p1,rp1)), xm(p2,rp2));
        vv[j] = xa(s, xm(RT[j*4+3], sgn[j]));
    }
    float z = vv[2];
    const float scale = 96.0f;
    float fx = xd(K[0], scale);
    float fy = xd(K[4], scale);
    float p0x = -xd(xsb(K[2], 96.0f), scale);
    float p0y = -xd(xsb(K[5], 96.0f), scale);
    float xn = xa(xd(xm(fx, vv[0]), z), p0x);
    float yn = xa(xd(xm(fy, vv[1]), z), p0y);
    verts[4*i+0] = xn; verts[4*i+1] = yn; verts[4*i+2] = z; verts[4*i+3] = 0.f;
}

// Pre-pass: depth-bucket histogram + global screen bbox of live faces
__global__ __launch_bounds__(256) void k_prehist(const int* __restrict__ faces,
        const float* __restrict__ verts, unsigned* __restrict__ hist,
        unsigned* __restrict__ gbb, int Fn){
    __shared__ unsigned lh[NBUCKET];
    int t = threadIdx.x;
    lh[t] = 0u;
    __syncthreads();
    int f = blockIdx.x*256 + t;
    float bxmn=INFINITY, bxmx=-INFINITY, bymn=INFINITY, bymx=-INFINITY;
    if (f < Fn){
        int i0 = faces[3*f+0], i1 = faces[3*f+1], i2 = faces[3*f+2];
        float x0=verts[4*i0+0], y0=verts[4*i0+1], z0=verts[4*i0+2];
        float x1=verts[4*i1+0], y1=verts[4*i1+1], z1=verts[4*i1+2];
        float x2=verts[4*i2+0], y2=verts[4*i2+1], z2=verts[4*i2+2];
        float area = xsb(xm(xsb(x1,x0), xsb(y2,y0)), xm(xsb(y1,y0), xsb(x2,x0)));
        bool ok = (area > EPS_F) && (z0 > 0.f) && (z1 > 0.f) && (z2 > 0.f);
        int b = 255;
        if (ok){
            float zmn = fminf(z0, fminf(z1, z2));
            b = zbucket(zmn);
            bxmn = fminf(x0, fminf(x1, x2)) - 1e-4f;
            bxmx = fmaxf(x0, fmaxf(x1, x2)) + 1e-4f;
            bymn = fminf(y0, fminf(y1, y2)) - 1e-4f;
            bymx = fmaxf(y0, fmaxf(y1, y2)) + 1e-4f;
        }
        atomicAdd(&lh[b], 1u);   // LDS atomic: cheap even when contended
    }
    // wave-reduce the bbox, one atomic set per wave
    #pragma unroll
    for (int s=1; s<64; s<<=1){
        bxmn = fminf(bxmn, __shfl_xor(bxmn, s, 64));
        bxmx = fmaxf(bxmx, __shfl_xor(bxmx, s, 64));
        bymn = fminf(bymn, __shfl_xor(bymn, s, 64));
        bymx = fmaxf(bymx, __shfl_xor(bymx, s, 64));
    }
    if ((t & 63) == 0){
        atomicMin(&gbb[0], fenc(bxmn));
        atomicMax(&gbb[1], fenc(bxmx));
        atomicMin(&gbb[2], fenc(bymn));
        atomicMax(&gbb[3], fenc(bymx));
    }
    __syncthreads();
    unsigned cc = lh[t];
    if (cc) atomicAdd(&hist[t], cc);   // non-returning, <=64 contenders/address
}

// Exclusive prefix over 256 bucket counts (single block)
__global__ __launch_bounds__(256) void k_scan(unsigned* __restrict__ hist){
    __shared__ unsigned s[NBUCKET];
    int t = threadIdx.x;
    unsigned v = hist[t];
    s[t] = v;
    __syncthreads();
    for (int d=1; d<NBUCKET; d<<=1){
        unsigned u = (t >= d) ? s[t-d] : 0u;
        __syncthreads();
        s[t] += u;
        __syncthreads();
    }
    hist[t] = s[t] - v;   // exclusive offsets; scatter's atomicAdd consumes them
}

// Face record (16 floats), written in depth-sorted order:
// q0: x0,y0,x1,y1 | q1: x2,y2,z0,z1 | q2: z2,ia,zmin,fidbits | q3: xmin,xmax,ymin,ymax
// Rank via LDS aggregation: ONE returning global atomic per (block,bucket), not per face.
__global__ __launch_bounds__(256) void k_scatter(const int* __restrict__ faces,
        const float* __restrict__ verts, float* __restrict__ rec,
        unsigned* __restrict__ hist, unsigned* __restrict__ chunkmin, int Fn){
    __shared__ unsigned lcnt[NBUCKET];
    __shared__ unsigned lbase[NBUCKET];
    int t = threadIdx.x;
    lcnt[t] = 0u;
    __syncthreads();
    int f = blockIdx.x*256 + t;
    bool valid = (f < Fn);
    float x0=0,y0=0,z0=0,x1=0,y1=0,z1=0,x2=0,y2=0,z2=0;
    float inv_area=0, xmn=0, xmx=0, ymn=0, ymx=0, zmn=0;
    int b = 255;
    unsigned rank = 0;
    if (valid){
        int i0 = faces[3*f+0], i1 = faces[3*f+1], i2 = faces[3*f+2];
        x0=verts[4*i0+0]; y0=verts[4*i0+1]; z0=verts[4*i0+2];
        x1=verts[4*i1+0]; y1=verts[4*i1+1]; z1=verts[4*i1+2];
        x2=verts[4*i2+0]; y2=verts[4*i2+1]; z2=verts[4*i2+2];
        float area = xsb(xm(xsb(x1,x0), xsb(y2,y0)), xm(xsb(y1,y0), xsb(x2,x0)));
        bool ok = (area > EPS_F) && (z0 > 0.f) && (z1 > 0.f) && (z2 > 0.f);
        inv_area = ok ? xd(1.0f, area) : 0.0f;
        if (ok){
            xmn = fminf(x0, fminf(x1, x2)) - 1e-4f;
            xmx = fmaxf(x0, fmaxf(x1, x2)) + 1e-4f;
            ymn = fminf(y0, fminf(y1, y2)) - 1e-4f;
            ymx = fmaxf(y0, fmaxf(y1, y2)) + 1e-4f;
            zmn = fminf(z0, fminf(z1, z2));
            b = zbucket(zmn);
        } else {
            xmn = INFINITY; xmx = -INFINITY; ymn = INFINITY; ymx = -INFINITY;
            zmn = INFINITY;
            b = 255;
        }
        rank = atomicAdd(&lcnt[b], 1u);   // LDS atomic: intra-block rank
    }
    __syncthreads();
    unsigned cc = lcnt[t];
    if (cc) lbase[t] = atomicAdd(&hist[t], cc);   // reserve global range for this block's bucket t
    __syncthreads();
    if (valid){
        unsigned pos = lbase[b] + rank;
        float4* q = (float4*)(rec + (size_t)pos*16);
        q[0] = make_float4(x0, y0, x1, y1);
        q[1] = make_float4(x2, y2, z0, z1);
        q[2] = make_float4(z2, inv_area, zmn, __int_as_float(f));
        q[3] = make_float4(xmn, xmx, ymn, ymx);
        if ((pos >> 8) < MAXCHUNK)
            atomicMin(&chunkmin[pos >> 8], __float_as_uint(zmn));  // positive floats: uint order == float order
    }
}

__global__ __launch_bounds__(256) void k_raster(const float* __restrict__ rec,
        const unsigned* __restrict__ chunkmin, const unsigned* __restrict__ gbb,
        ull* __restrict__ keys, int Fn){
    __shared__ float lds[CHUNK*12];   // 12 floats per face
    __shared__ float zl[CHUNK];       // zmin of survivors, compacted
    __shared__ int   slist[CHUNK];    // survivor chunk-local indices, compacted
    __shared__ int   wcnt[4];
    __shared__ float suff[MAXCHUNK];  // suffix-min of chunk zmins
    int tid = threadIdx.x;
    int nchunk = Fn / CHUNK;
    // wave0: inclusive suffix-min over chunk zmins (64 lanes, shfl scan)
    if (tid < MAXCHUNK){
        float v = (tid < nchunk) ? __uint_as_float(chunkmin[tid]) : INFINITY;
        #pragma unroll
        for (int s=1; s<MAXCHUNK; s<<=1){
            int src = tid + s; if (src > MAXCHUNK-1) src = MAXCHUNK-1;
            float o = __shfl(v, src, 64);
            v = fminf(v, o);
        }
        suff[tid] = v;
    }
    int ix = blockIdx.x*TILE + (tid & 15);
    int iy = blockIdx.y*TILE + (tid >> 4);
    int pix = iy*W_ + ix;
    float px = pixcoord(ix, (float)W_);
    float py = pixcoord(iy, (float)H_);
    float tx_hi = pixcoord(blockIdx.x*TILE,          (float)W_);
    float tx_lo = pixcoord(blockIdx.x*TILE + TILE-1, (float)W_);
    float ty_hi = pixcoord(blockIdx.y*TILE,          (float)H_);
    float ty_lo = pixcoord(blockIdx.y*TILE + TILE-1, (float)H_);
    float gx0 = fdec(gbb[0]), gx1 = fdec(gbb[1]);
    float gy0 = fdec(gbb[2]), gy1 = fdec(gbb[3]);
    // pixel outside the union of all live-face bboxes can never be hit
    bool alive = (px >= gx0) && (px <= gx1) && (py >= gy0) && (py <= gy1);
    int lane = tid & 63, wv = tid >> 6;

    float zcut = INFINITY;       // skip threshold: min(local best z, global best z)
    ull localkey = 0xFFFFFFFFFFFFFFFFULL;  // best locally-found candidate
    ull published = 0xFFFFFFFFFFFFFFFFULL; // what we've already pushed to keys[]
    __syncthreads();             // suff[] ready

    for (int c = (int)blockIdx.z; c < nchunk; c += NSLICE){
        // share depth convergence across slice blocks (stale reads are conservative)
        ull g = __hip_atomic_load(&keys[pix], __ATOMIC_RELAXED, __HIP_MEMORY_SCOPE_AGENT);
        float zg = __uint_as_float((unsigned)(g >> 32));   // NaN if key empty -> fminf ignores
        zcut = fminf(zcut, zg);
        // block-wide break: every remaining face (zmin >= suff[c]) would be pre-check-skipped
        float sc = (c < MAXCHUNK) ? suff[c] : 0.0f;
        int done = (!alive || !(xm(sc, 0.999f) < zcut)) ? 1 : 0;
        if (__syncthreads_and(done)) break;    // barrier also protects lds reuse

        int base = c*CHUNK;
        const float4* gq = (const float4*)(rec + (size_t)(base + tid)*16);
        float4 q0 = gq[0], q1 = gq[1], q2 = gq[2], q3 = gq[3];
        // bbox-vs-tile overlap; dead faces have empty bbox -> rejected
        bool keep = (q3.x <= tx_hi) && (q3.y >= tx_lo) && (q3.z <= ty_hi) && (q3.w >= ty_lo);
        float4* l = (float4*)(lds + tid*12);
        l[0] = q0; l[1] = q1; l[2] = q2;
        ull m = __ballot(keep);
        if (lane == 0) wcnt[wv] = __popcll(m);
        __syncthreads();
        int basecnt = 0;
        #pragma unroll
        for (int w2 = 0; w2 < 4; ++w2) if (w2 < wv) basecnt += wcnt[w2];
        if (keep){
            int p = basecnt + __popcll(m & ((1ULL << lane) - 1ULL));
            slist[p] = tid;
            zl[p] = q2.z;   // zmin
        }
        int nsurv = wcnt[0] + wcnt[1] + wcnt[2] + wcnt[3];
        __syncthreads();

        for (int k = 0; k < nsurv; k++){
            float zminf = zl[k];
            // conservative depth pre-check (margin 0.999 covers interpolation rounding;
            // strict < keeps exact-z ties evaluated for fid tie-break)
            if (!(xm(zminf, 0.999f) < zcut)) continue;
            int j = slist[k];
            const float* r = lds + j*12;
            float x0=r[0], y0=r[1], x1=r[2], y1=r[3], x2=r[4], y2=r[5];
            float dx0=xsb(x0,px), dx1=xsb(x1,px), dx2=xsb(x2,px);
            float dy0=xsb(y0,py), dy1=xsb(y1,py), dy2=xsb(y2,py);
            // edge functions: sign(e_i) == sign(w_i) since ia>0
            float e0 = xsb(xm(dx1,dy2), xm(dy1,dx2));
            float e1 = xsb(xm(dx2,dy0), xm(dy2,dx0));
            float e2 = xsb(xm(dx0,dy1), xm(dy0,dx1));
            if (e0 >= 0.f && e1 >= 0.f && e2 >= 0.f){
                float z0=r[6], z1=r[7], z2=r[8], ia=r[9];
                float w0 = xm(e0, ia), w1 = xm(e1, ia), w2 = xm(e2, ia);
                float l0 = xm(xm(w0,z1),z2);
                float l1 = xm(xm(z0,w1),z2);
                float l2 = xm(xm(z0,z1),w2);
                float s  = xa(xa(l0,l1),l2);
                float dn = (s == 0.f) ? 1.0f : s;
                float b0 = fmaxf(xd(l0,dn), 0.f);
                float b1 = fmaxf(xd(l1,dn), 0.f);
                float b2 = fmaxf(xd(l2,dn), 0.f);
                float bs = fmaxf(xa(xa(b0,b1),b2), EPS_F);
                b0 = xd(b0,bs); b1 = xd(b1,bs); b2 = xd(b2,bs);
                float zp = xa(xa(xm(b0,z0),xm(b1,z1)),xm(b2,z2));
                // packed (z, orig_fid) key: exact argmin-first tie semantics
                ull ck = (((ull)__float_as_uint(zp)) << 32) | (unsigned)__float_as_int(r[11]);
                if (ck < localkey) localkey = ck;
                zcut = fminf(zcut, zp);
            }
        }
        // publish improvements NOW so concurrent slice blocks can break early
        if (localkey < published){
            atomicMin(&keys[pix], localkey);
            published = localkey;
        }
    }
    if (localkey < published) atomicMin(&keys[pix], localkey);
}

// Fused resolve + shade: 64 lanes per pixel (lane = channel), 4 pixels/block.
// Face record rebuilt from verts/faces (rec is depth-sorted; keys hold orig fid).
__global__ __launch_bounds__(256) void k_post(const ull* __restrict__ keys,
        const float* __restrict__ verts, const float* __restrict__ feats,
        const int* __restrict__ faces, float* __restrict__ out){
    int grp = threadIdx.x >> 6;
    int c = threadIdx.x & 63;
    int pix = blockIdx.x*4 + grp;
    float* p2f  = out + OFF_P2F;
    float* zbuf = out + OFF_ZBUF;
    float* bary = out + OFF_BARY;
    float* dist = out + OFF_DIST;
    ull key = keys[pix];
    if (key == 0xFFFFFFFFFFFFFFFFULL){
        out[OFF_FEATS + pix*C_ + c] = 0.0f;
        if (c == 0){
            p2f[pix] = -1.0f; zbuf[pix] = -1.0f; dist[pix] = -1.0f;
        }
        if (c < 3) bary[3*pix+c] = -1.0f;
        return;
    }
    int f = (int)(key & 0xFFFFFFFFu);
    float z = __uint_as_float((unsigned)(key >> 32));
    int ix = pix % W_, iy = pix / W_;
    float px = pixcoord(ix, (float)W_);
    float py = pixcoord(iy, (float)H_);
    int i0 = faces[3*f+0], i1 = faces[3*f+1], i2 = faces[3*f+2];
    float x0=verts[4*i0+0], y0=verts[4*i0+1], z0=verts[4*i0+2];
    float x1=verts[4*i1+0], y1=verts[4*i1+1], z1=verts[4*i1+2];
    float x2=verts[4*i2+0], y2=verts[4*i2+1], z2=verts[4*i2+2];
    float area = xsb(xm(xsb(x1,x0), xsb(y2,y0)), xm(xsb(y1,y0), xsb(x2,x0)));
    float ia = xd(1.0f, area);   // face is a hit -> guaranteed ok, area > EPS
    float w0 = xm(xsb(xm(xsb(x1,px),xsb(y2,py)), xm(xsb(y1,py),xsb(x2,px))), ia);
    float w1 = xm(xsb(xm(xsb(x2,px),xsb(y0,py)), xm(xsb(y2,py),xsb(x0,px))), ia);
    float w2 = xm(xsb(xm(xsb(x0,px),xsb(y1,py)), xm(xsb(y0,py),xsb(x1,px))), ia);
    float l0 = xm(xm(w0,z1),z2);
    float l1 = xm(xm(z0,w1),z2);
    float l2 = xm(xm(z0,z1),w2);
    float s  = xa(xa(l0,l1),l2);
    float dn = (s == 0.f) ? 1.0f : s;
    float b0 = fmaxf(xd(l0,dn), 0.f);
    float b1 = fmaxf(xd(l1,dn), 0.f);
    float b2 = fmaxf(xd(l2,dn), 0.f);
    float bs = fmaxf(xa(xa(b0,b1),b2), EPS_F);
    b0 = xd(b0,bs); b1 = xd(b1,bs); b2 = xd(b2,bs);
    float res = xa(xa(xm(b0, feats[i0*C_ + c]), xm(b1, feats[i1*C_ + c])),
                   xm(b2, feats[i2*C_ + c]));
    out[OFF_FEATS + pix*C_ + c] = res;
    if (c == 0){
        p2f[pix] = (float)f; zbuf[pix] = z; dist[pix] = 0.0f;
    }
    if (c < 3){
        float bb = (c == 0) ? b0 : ((c == 1) ? b1 : b2);
        bary[3*pix+c] = bb;
    }
}

extern "C" void kernel_launch(void* const* d_in, const int* in_sizes, int n_in,
                              void* d_out, int out_size, void* d_ws, size_t ws_size,
                              hipStream_t stream) {
    const float* positions = (const float*)d_in[0];
    const float* features  = (const float*)d_in[1];
    const int*   faces     = (const int*)  d_in[2];
    const float* K         = (const float*)d_in[3];
    const float* RT        = (const float*)d_in[4];
    int V  = in_sizes[0] / 3;   // 8192
    int Fn = in_sizes[2] / 3;   // 16384

    float* verts = (float*)d_ws;                        // V*4 floats
    float* rec   = verts + (size_t)V*4;                 // Fn*16 floats (depth-sorted)
    ull*   keys  = (ull*)(rec + (size_t)Fn*16);         // H*W keys
    unsigned* hist     = (unsigned*)(keys + H_*W_);     // 256 bucket counts/offsets
    unsigned* chunkmin = hist + NBUCKET;                // 64 chunk zmins (uint bits)
    unsigned* gbb      = chunkmin + MAXCHUNK;           // global bbox (enc uint x4)

    int initN = H_*W_;  // covers keys (36864), verts (8192), hist/chunkmin/gbb
    k_init<<<(initN+255)/256, 256, 0, stream>>>(positions, K, RT, verts, keys, hist, chunkmin, gbb, V);
    k_prehist<<<(Fn+255)/256, 256, 0, stream>>>(faces, verts, hist, gbb, Fn);
    k_scan<<<1, 256, 0, stream>>>(hist);
    k_scatter<<<(Fn+255)/256, 256, 0, stream>>>(faces, verts, rec, hist, chunkmin, Fn);
    dim3 rg(W_/TILE, H_/TILE, NSLICE);
    k_raster<<<rg, dim3(256,1,1), 0, stream>>>(rec, chunkmin, gbb, keys, Fn);
    k_post<<<(H_*W_)/4, 256, 0, stream>>>(keys, verts, features, faces, (float*)d_out);
}

// Round 3
// 212.485 us; speedup vs baseline: 1.5144x; 1.1630x over previous
//
#include <hip/hip_runtime.h>
#include <stdint.h>

#define H_ 192
#define W_ 192
#define C_ 64
#define EPS_F 1e-8f
#define TILE 16
#define CHUNK 256
#define NSLICE 8
#define NBUCKET 256
#define MAXCHUNK 64

typedef unsigned long long ull;

// Output layout (floats), concatenated in reference return order:
// feats (H*W*C) | p2f (H*W) | zbuf (H*W) | bary (H*W*3) | dists (H*W)
#define OFF_FEATS 0
#define OFF_P2F   (H_*W_*C_)
#define OFF_ZBUF  (OFF_P2F + H_*W_)
#define OFF_BARY  (OFF_ZBUF + H_*W_)
#define OFF_DIST  (OFF_BARY + H_*W_*3)

// IEEE-exact ops (block FMA contraction; match numpy float32 op-for-op)
__device__ __forceinline__ float xm(float a, float b){ return __fmul_rn(a,b); }
__device__ __forceinline__ float xa(float a, float b){ return __fadd_rn(a,b); }
__device__ __forceinline__ float xsb(float a, float b){ return __fsub_rn(a,b); }
__device__ __forceinline__ float xd(float a, float b){ return __fdiv_rn(a,b); }

__device__ __forceinline__ float pixcoord(int i, float dim){
    float t = xa(xm(2.0f, (float)i), 1.0f);
    return xsb(1.0f, xd(t, dim));
}

// depth bucket: fixed mapping (perf-only; correctness holds for any mapping)
__device__ __forceinline__ int zbucket(float zmn){
    int b = (int)((zmn - 2.0f) * 64.0f);
    return b < 0 ? 0 : (b > 254 ? 254 : b);
}

// Vertex transform — IDENTICAL op order everywhere (pre/scatter/post recompute
// the same bits; no verts buffer needed).
__device__ __forceinline__ float3 tv(const float* __restrict__ pos,
        const float* __restrict__ K, const float* __restrict__ RT, int i){
    float p0 = pos[3*i+0], p1 = pos[3*i+1], p2 = pos[3*i+2];
    const float sgn[3] = {-1.f, -1.f, 1.f};
    float vv[3];
    #pragma unroll
    for (int j=0;j<3;j++){
        float rp0 = xm(RT[j*4+0], sgn[j]);
        float rp1 = xm(RT[j*4+1], sgn[j]);
        float rp2 = xm(RT[j*4+2], sgn[j]);
        float s = xa(xa(xm(p0,rp0), xm(p1,rp1)), xm(p2,rp2));
        vv[j] = xa(s, xm(RT[j*4+3], sgn[j]));
    }
    float z = vv[2];
    float fx = xd(K[0], 96.0f);
    float fy = xd(K[4], 96.0f);
    float p0x = -xd(xsb(K[2], 96.0f), 96.0f);
    float p0y = -xd(xsb(K[5], 96.0f), 96.0f);
    float xn = xa(xd(xm(fx, vv[0]), z), p0x);
    float yn = xa(xd(xm(fy, vv[1]), z), p0y);
    return make_float3(xn, yn, z);
}

// Launch 1: clear keys/chunkmin + per-block slab histogram + per-block bbox.
// No global atomics on hist (slab is fully overwritten -> no clear needed).
__global__ __launch_bounds__(256) void k_pre(const float* __restrict__ pos,
        const float* __restrict__ K, const float* __restrict__ RT,
        const int* __restrict__ faces, ull* __restrict__ keys,
        unsigned* __restrict__ slab, float* __restrict__ slabb,
        unsigned* __restrict__ chunkmin, int Fn, int npre){
    int t = threadIdx.x, B = blockIdx.x;
    for (int i = B*256 + t; i < H_*W_; i += npre*256) keys[i] = 0xFFFFFFFFFFFFFFFFULL;
    if (B == 0 && t < MAXCHUNK) chunkmin[t] = 0x7F800000u;   // +INF bits
    __shared__ unsigned lh[NBUCKET];
    __shared__ float wb[16];
    lh[t] = 0u;
    __syncthreads();
    int f = B*256 + t;
    float bxmn=INFINITY, bxmx=-INFINITY, bymn=INFINITY, bymx=-INFINITY;
    if (f < Fn){
        int i0 = faces[3*f+0], i1 = faces[3*f+1], i2 = faces[3*f+2];
        float3 v0 = tv(pos,K,RT,i0), v1 = tv(pos,K,RT,i1), v2 = tv(pos,K,RT,i2);
        float area = xsb(xm(xsb(v1.x,v0.x), xsb(v2.y,v0.y)), xm(xsb(v1.y,v0.y), xsb(v2.x,v0.x)));
        bool ok = (area > EPS_F) && (v0.z > 0.f) && (v1.z > 0.f) && (v2.z > 0.f);
        int b = 255;
        if (ok){
            float zmn = fminf(v0.z, fminf(v1.z, v2.z));
            b = zbucket(zmn);
            bxmn = fminf(v0.x, fminf(v1.x, v2.x)) - 1e-4f;
            bxmx = fmaxf(v0.x, fmaxf(v1.x, v2.x)) + 1e-4f;
            bymn = fminf(v0.y, fminf(v1.y, v2.y)) - 1e-4f;
            bymx = fmaxf(v0.y, fmaxf(v1.y, v2.y)) + 1e-4f;
        }
        atomicAdd(&lh[b], 1u);
    }
    #pragma unroll
    for (int s2=1; s2<64; s2<<=1){
        bxmn = fminf(bxmn, __shfl_xor(bxmn, s2, 64));
        bxmx = fmaxf(bxmx, __shfl_xor(bxmx, s2, 64));
        bymn = fminf(bymn, __shfl_xor(bymn, s2, 64));
        bymx = fmaxf(bymx, __shfl_xor(bymx, s2, 64));
    }
    if ((t & 63) == 0){
        int w = t >> 6;
        wb[w*4+0]=bxmn; wb[w*4+1]=bxmx; wb[w*4+2]=bymn; wb[w*4+3]=bymx;
    }
    __syncthreads();
    if (t == 0){
        slabb[B*4+0] = fminf(fminf(wb[0],wb[4]),  fminf(wb[8], wb[12]));
        slabb[B*4+1] = fmaxf(fmaxf(wb[1],wb[5]),  fmaxf(wb[9], wb[13]));
        slabb[B*4+2] = fminf(fminf(wb[2],wb[6]),  fminf(wb[10],wb[14]));
        slabb[B*4+3] = fmaxf(fmaxf(wb[3],wb[7]),  fmaxf(wb[11],wb[15]));
    }
    slab[B*256 + t] = lh[t];
}

// Launch 2: each block redundantly sums+scans the slab (no ordering deps),
// computes its faces' depth-sorted positions, writes 20-float records + the
// 1/z plane coefficients, chunk zmins, and the global bbox (same-value write).
// Record (5 float4): q0 x0,y0,x1,y1 | q1 x2,y2,z0,z1 | q2 z2,ia,fid,zmin
//                    q3 A,B,C,0     | q4 xmn,xmx,ymn,ymx
__global__ __launch_bounds__(256) void k_scatter(const float* __restrict__ pos,
        const float* __restrict__ K, const float* __restrict__ RT,
        const int* __restrict__ faces, const unsigned* __restrict__ slab,
        const float* __restrict__ slabb, float* __restrict__ gbbf,
        float* __restrict__ rec, unsigned* __restrict__ chunkmin, int Fn, int npre){
    __shared__ unsigned lcnt[NBUCKET], gst[NBUCKET], cpre[NBUCKET], ssc[NBUCKET];
    int t = threadIdx.x, B = blockIdx.x;
    lcnt[t] = 0u;
    unsigned pre = 0, tot = 0;
    for (int b2 = 0; b2 < npre; b2++){
        unsigned v = slab[b2*256 + t];
        if (b2 < B) pre += v;
        tot += v;
    }
    cpre[t] = pre; ssc[t] = tot;
    __syncthreads();
    for (int d=1; d<NBUCKET; d<<=1){
        unsigned u = (t >= d) ? ssc[t-d] : 0u;
        __syncthreads();
        ssc[t] += u;
        __syncthreads();
    }
    gst[t] = ssc[t] - tot;   // exclusive global bucket start
    if (t < 4){   // global bbox: every block computes the identical value
        float m = slabb[t];
        for (int b2=1; b2<npre; b2++){
            float v = slabb[b2*4 + t];
            m = (t & 1) ? fmaxf(m, v) : fminf(m, v);
        }
        gbbf[t] = m;
    }
    __syncthreads();
    int f = B*256 + t;
    if (f >= Fn) return;
    int i0 = faces[3*f+0], i1 = faces[3*f+1], i2 = faces[3*f+2];
    float3 v0 = tv(pos,K,RT,i0), v1 = tv(pos,K,RT,i1), v2 = tv(pos,K,RT,i2);
    float x0=v0.x,y0=v0.y,z0=v0.z, x1=v1.x,y1=v1.y,z1=v1.z, x2=v2.x,y2=v2.y,z2=v2.z;
    float area = xsb(xm(xsb(x1,x0), xsb(y2,y0)), xm(xsb(y1,y0), xsb(x2,x0)));
    bool ok = (area > EPS_F) && (z0 > 0.f) && (z1 > 0.f) && (z2 > 0.f);
    float inv_area = ok ? xd(1.0f, area) : 0.0f;
    float xmn, xmx, ymn, ymx, zmn, Ap=0.f, Bp=0.f, Cp=0.f;
    int b = 255;
    if (ok){
        xmn = fminf(x0, fminf(x1, x2)) - 1e-4f;
        xmx = fmaxf(x0, fmaxf(x1, x2)) + 1e-4f;
        ymn = fminf(y0, fminf(y1, y2)) - 1e-4f;
        ymx = fmaxf(y0, fmaxf(y1, y2)) + 1e-4f;
        zmn = fminf(z0, fminf(z1, z2));
        b = zbucket(zmn);
        // 1/zp = C + A*px + B*py  (filter-only; margins absorb FP error)
        float iz0 = 1.f/z0, iz1 = 1.f/z1, iz2 = 1.f/z2;
        Ap = inv_area * ((y1-y2)*iz0 + (y2-y0)*iz1 + (y0-y1)*iz2);
        Bp = inv_area * ((x2-x1)*iz0 + (x0-x2)*iz1 + (x1-x0)*iz2);
        Cp = inv_area * ((x1*y2-x2*y1)*iz0 + (x2*y0-x0*y2)*iz1 + (x0*y1-x1*y0)*iz2);
    } else {
        xmn = INFINITY; xmx = -INFINITY; ymn = INFINITY; ymx = -INFINITY;
        zmn = INFINITY;
    }
    unsigned rank = atomicAdd(&lcnt[b], 1u);          // intra-block rank (LDS)
    unsigned p = gst[b] + cpre[b] + rank;             // unique depth-sorted slot
    float4* q = (float4*)(rec + (size_t)p*20);
    q[0] = make_float4(x0, y0, x1, y1);
    q[1] = make_float4(x2, y2, z0, z1);
    q[2] = make_float4(z2, inv_area, __int_as_float(f), zmn);
    q[3] = make_float4(Ap, Bp, Cp, 0.f);
    q[4] = make_float4(xmn, xmx, ymn, ymx);
    if ((p >> 8) < MAXCHUNK)
        atomicMin(&chunkmin[p >> 8], __float_as_uint(zmn));  // positive floats: uint order == float order
}

// Launch 3: tiled raster. All skips are provably conservative vs the FINAL key
// (zcut >= final zbest always), so output is timing-independent.
__global__ __launch_bounds__(256) void k_raster(const float* __restrict__ rec,
        const unsigned* __restrict__ chunkmin, const float* __restrict__ gbbf,
        ull* __restrict__ keys, int Fn){
    __shared__ float lds[CHUNK*12];   // 12 floats per face
    __shared__ float zl[CHUNK];       // per-tile z lower bound of survivors
    __shared__ int   slist[CHUNK];
    __shared__ int   wcnt[4];
    __shared__ float suff[MAXCHUNK];  // suffix-min of chunk zmins
    int tid = threadIdx.x;
    int nchunk = (Fn + CHUNK - 1) / CHUNK;
    if (tid < MAXCHUNK){
        float v = (tid < nchunk) ? __uint_as_float(chunkmin[tid]) : INFINITY;
        #pragma unroll
        for (int s=1; s<MAXCHUNK; s<<=1){
            int src = tid + s; if (src > MAXCHUNK-1) src = MAXCHUNK-1;
            float o = __shfl(v, src, 64);
            v = fminf(v, o);
        }
        suff[tid] = v;
    }
    int ix = blockIdx.x*TILE + (tid & 15);
    int iy = blockIdx.y*TILE + (tid >> 4);
    int pix = iy*W_ + ix;
    float px = pixcoord(ix, (float)W_);
    float py = pixcoord(iy, (float)H_);
    float tx_hi = pixcoord(blockIdx.x*TILE,          (float)W_);
    float tx_lo = pixcoord(blockIdx.x*TILE + TILE-1, (float)W_);
    float ty_hi = pixcoord(blockIdx.y*TILE,          (float)H_);
    float ty_lo = pixcoord(blockIdx.y*TILE + TILE-1, (float)H_);
    bool alive = (px >= gbbf[0]) && (px <= gbbf[1]) && (py >= gbbf[2]) && (py <= gbbf[3]);
    int lane = tid & 63, wv = tid >> 6;

    float zcut = INFINITY;
    ull localkey = 0xFFFFFFFFFFFFFFFFULL;
    ull published = 0xFFFFFFFFFFFFFFFFULL;
    __syncthreads();             // suff[] ready

    for (int c = (int)blockIdx.z; c < nchunk; c += NSLICE){
        ull g = __hip_atomic_load(&keys[pix], __ATOMIC_RELAXED, __HIP_MEMORY_SCOPE_AGENT);
        float zg = __uint_as_float((unsigned)(g >> 32));   // NaN if empty -> fminf ignores
        zcut = fminf(zcut, zg);
        float sc = (c < MAXCHUNK) ? suff[c] : 0.0f;
        int done = (!alive || !(xm(sc, 0.999f) < zcut)) ? 1 : 0;
        if (__syncthreads_and(done)) break;    // barrier also protects lds reuse

        int fi = c*CHUNK + tid;
        float4 q0 = make_float4(0,0,0,0), q1 = q0, q2 = q0;
        bool keep = false;
        float zb = 0.f;
        if (fi < Fn){
            const float4* gq = (const float4*)(rec + (size_t)fi*20);
            q0 = gq[0]; q1 = gq[1]; q2 = gq[2];
            float4 q3 = gq[3], q4 = gq[4];
            keep = (q4.x <= tx_hi) && (q4.y >= tx_lo) && (q4.z <= ty_hi) && (q4.w >= ty_lo);
            if (keep){
                // tile z lower bound from the linear 1/z plane (corner max, with margin)
                float ax = (q3.x > 0.f) ? tx_hi : tx_lo;
                float by = (q3.y > 0.f) ? ty_hi : ty_lo;
                float Nmax = q3.z + q3.x*ax + q3.y*by;
                float M = fabsf(q3.x*ax) + fabsf(q3.y*by) + fabsf(q3.z);
                float Nub = Nmax + 1e-5f*M + 1e-30f;
                if (Nub <= 0.f) keep = false;          // no coverage possible in tile
                else zb = fmaxf(1.f/Nub, q2.w);        // max(plane bound, face zmin)
            }
        }
        float4* l = (float4*)(lds + tid*12);
        l[0] = q0; l[1] = q1; l[2] = q2;
        ull m = __ballot(keep);
        if (lane == 0) wcnt[wv] = __popcll(m);
        __syncthreads();
        int basecnt = 0;
        #pragma unroll
        for (int w2 = 0; w2 < 4; ++w2) if (w2 < wv) basecnt += wcnt[w2];
        if (keep){
            int p = basecnt + __popcll(m & ((1ULL << lane) - 1ULL));
            slist[p] = tid;
            zl[p] = zb;
        }
        int nsurv = wcnt[0] + wcnt[1] + wcnt[2] + wcnt[3];
        __syncthreads();

        for (int k = 0; k < nsurv; k++){
            float zbl = zl[k];
            if (!(xm(zbl, 0.999f) < zcut)) continue;   // conservative tile-z pre-check
            int j = slist[k];
            const float* r = lds + j*12;
            float x0=r[0], y0=r[1], x1=r[2], y1=r[3], x2=r[4], y2=r[5];
            float dx0=xsb(x0,px), dx1=xsb(x1,px), dx2=xsb(x2,px);
            float dy0=xsb(y0,py), dy1=xsb(y1,py), dy2=xsb(y2,py);
            float e0 = xsb(xm(dx1,dy2), xm(dy1,dx2));
            float e1 = xsb(xm(dx2,dy0), xm(dy2,dx0));
            float e2 = xsb(xm(dx0,dy1), xm(dy0,dx1));
            if (e0 >= 0.f && e1 >= 0.f && e2 >= 0.f){
                float z0=r[6], z1=r[7], z2=r[8], ia=r[9];
                float w0 = xm(e0, ia), w1 = xm(e1, ia), w2 = xm(e2, ia);
                float l0 = xm(xm(w0,z1),z2);
                float l1 = xm(xm(z0,w1),z2);
                float l2 = xm(xm(z0,z1),w2);
                float s  = xa(xa(l0,l1),l2);
                // cheap-z filter (1 divide): za ~ exact zp within ~3e-7 rel.
                // Skip only when provably worse than zcut; NaN (s==0) falls through.
                float za = (l0*z0 + l1*z1 + l2*z2) / s;
                if (za*0.99999f >= zcut) continue;
                float dn = (s == 0.f) ? 1.0f : s;
                float b0 = fmaxf(xd(l0,dn), 0.f);
                float b1 = fmaxf(xd(l1,dn), 0.f);
                float b2 = fmaxf(xd(l2,dn), 0.f);
                float bs = fmaxf(xa(xa(b0,b1),b2), EPS_F);
                b0 = xd(b0,bs); b1 = xd(b1,bs); b2 = xd(b2,bs);
                float zp = xa(xa(xm(b0,z0),xm(b1,z1)),xm(b2,z2));
                ull ck = (((ull)__float_as_uint(zp)) << 32) | (unsigned)__float_as_int(r[10]);
                if (ck < localkey) localkey = ck;
                zcut = fminf(zcut, zp);
            }
        }
        if (localkey < published){     // publish so other slice blocks can break
            atomicMin(&keys[pix], localkey);
            published = localkey;
        }
    }
    if (localkey < published) atomicMin(&keys[pix], localkey);
}

// Launch 4: resolve + shade; 64 lanes per pixel (lane = channel), 4 pixels/block.
// Vertices re-transformed (bit-identical tv()); rec not needed here.
__global__ __launch_bounds__(256) void k_post(const ull* __restrict__ keys,
        const float* __restrict__ pos, const float* __restrict__ K,
        const float* __restrict__ RT, const float* __restrict__ feats,
        const int* __restrict__ faces, float* __restrict__ out){
    int grp = threadIdx.x >> 6;
    int c = threadIdx.x & 63;
    int pix = blockIdx.x*4 + grp;
    float* p2f  = out + OFF_P2F;
    float* zbuf = out + OFF_ZBUF;
    float* bary = out + OFF_BARY;
    float* dist = out + OFF_DIST;
    ull key = keys[pix];
    if (key == 0xFFFFFFFFFFFFFFFFULL){
        out[OFF_FEATS + pix*C_ + c] = 0.0f;
        if (c == 0){
            p2f[pix] = -1.0f; zbuf[pix] = -1.0f; dist[pix] = -1.0f;
        }
        if (c < 3) bary[3*pix+c] = -1.0f;
        return;
    }
    int f = (int)(key & 0xFFFFFFFFu);
    float z = __uint_as_float((unsigned)(key >> 32));
    int ix = pix % W_, iy = pix / W_;
    float px = pixcoord(ix, (float)W_);
    float py = pixcoord(iy, (float)H_);
    int i0 = faces[3*f+0], i1 = faces[3*f+1], i2 = faces[3*f+2];
    float3 v0 = tv(pos,K,RT,i0), v1 = tv(pos,K,RT,i1), v2 = tv(pos,K,RT,i2);
    float x0=v0.x,y0=v0.y,z0=v0.z, x1=v1.x,y1=v1.y,z1=v1.z, x2=v2.x,y2=v2.y,z2=v2.z;
    float area = xsb(xm(xsb(x1,x0), xsb(y2,y0)), xm(xsb(y1,y0), xsb(x2,x0)));
    float ia = xd(1.0f, area);   // hit face -> guaranteed ok, area > EPS
    float w0 = xm(xsb(xm(xsb(x1,px),xsb(y2,py)), xm(xsb(y1,py),xsb(x2,px))), ia);
    float w1 = xm(xsb(xm(xsb(x2,px),xsb(y0,py)), xm(xsb(y2,py),xsb(x0,px))), ia);
    float w2 = xm(xsb(xm(xsb(x0,px),xsb(y1,py)), xm(xsb(y0,py),xsb(x1,px))), ia);
    float l0 = xm(xm(w0,z1),z2);
    float l1 = xm(xm(z0,w1),z2);
    float l2 = xm(xm(z0,z1),w2);
    float s  = xa(xa(l0,l1),l2);
    float dn = (s == 0.f) ? 1.0f : s;
    float b0 = fmaxf(xd(l0,dn), 0.f);
    float b1 = fmaxf(xd(l1,dn), 0.f);
    float b2 = fmaxf(xd(l2,dn), 0.f);
    float bs = fmaxf(xa(xa(b0,b1),b2), EPS_F);
    b0 = xd(b0,bs); b1 = xd(b1,bs); b2 = xd(b2,bs);
    float res = xa(xa(xm(b0, feats[i0*C_ + c]), xm(b1, feats[i1*C_ + c])),
                   xm(b2, feats[i2*C_ + c]));
    out[OFF_FEATS + pix*C_ + c] = res;
    if (c == 0){
        p2f[pix] = (float)f; zbuf[pix] = z; dist[pix] = 0.0f;
    }
    if (c < 3){
        float bb = (c == 0) ? b0 : ((c == 1) ? b1 : b2);
        bary[3*pix+c] = bb;
    }
}

extern "C" void kernel_launch(void* const* d_in, const int* in_sizes, int n_in,
                              void* d_out, int out_size, void* d_ws, size_t ws_size,
                              hipStream_t stream) {
    const float* positions = (const float*)d_in[0];
    const float* features  = (const float*)d_in[1];
    const int*   faces     = (const int*)  d_in[2];
    const float* K         = (const float*)d_in[3];
    const float* RT        = (const float*)d_in[4];
    int Fn = in_sizes[2] / 3;   // 16384
    int npre = (Fn + 255) / 256;

    float* rec = (float*)d_ws;                            // Fn*20 floats (depth-sorted)
    ull*   keys = (ull*)(rec + (size_t)Fn*20);            // H*W keys
    unsigned* slab = (unsigned*)(keys + H_*W_);           // npre*256 block histograms
    float* slabb = (float*)(slab + (size_t)npre*256);     // npre*4 block bboxes
    float* gbbf  = slabb + (size_t)npre*4;                // 4 global bbox
    unsigned* chunkmin = (unsigned*)(gbbf + 4);           // 64 chunk zmins (uint bits)

    k_pre<<<npre, 256, 0, stream>>>(positions, K, RT, faces, keys, slab, slabb, chunkmin, Fn, npre);
    k_scatter<<<npre, 256, 0, stream>>>(positions, K, RT, faces, slab, slabb, gbbf, rec, chunkmin, Fn, npre);
    dim3 rg(W_/TILE, H_/TILE, NSLICE);
    k_raster<<<rg, dim3(256,1,1), 0, stream>>>(rec, chunkmin, gbbf, keys, Fn);
    k_post<<<(H_*W_)/4, 256, 0, stream>>>(keys, positions, K, RT, features, faces, (float*)d_out);
}